// Round 14
// baseline (497.741 us; speedup 1.0000x reference)
//
#include <hip/hip_runtime.h>
#include <math.h>

#define N_NODES 50000
#define C_DIM   128
#define E_EDGES 1600000
#define Q_PAIRS 500000
#define H_DIM   256
#define N_CLS   2
#define BN_EPS  1e-5f

#define GE_BLK  6250   // (E_EDGES+255)/256

typedef __attribute__((ext_vector_type(8))) short bf16x8;
typedef __attribute__((ext_vector_type(4))) short s16x4;
typedef __attribute__((ext_vector_type(4))) unsigned short u16x4;
typedef __attribute__((ext_vector_type(4))) float f32x4;

#define VMCNT0 asm volatile("s_waitcnt vmcnt(0)" ::: "memory")
#define VMCNT1 asm volatile("s_waitcnt vmcnt(1)" ::: "memory")
#define VMCNT2 asm volatile("s_waitcnt vmcnt(2)" ::: "memory")
#define SBAR do { __builtin_amdgcn_s_barrier(); \
                  __builtin_amdgcn_sched_barrier(0); } while (0)

#define DEG_SCALE 2097152.0f   // 2^21 fixed point for packed degree

__device__ __forceinline__ unsigned short f2bf(float x) {   // RNE f32->bf16 bits
    unsigned u = __float_as_uint(x);
    u += 0x7fffu + ((u >> 16) & 1u);
    return (unsigned short)(u >> 16);
}
__device__ __forceinline__ float bf2f(unsigned short h) {
    return __uint_as_float(((unsigned)h) << 16);
}
// packed 2x bf16 (lo=a, hi=b) via HW converter
__device__ __forceinline__ unsigned cvtpk(float a, float b) {
    unsigned r;
    asm("v_cvt_pk_bf16_f32 %0, %1, %2" : "=v"(r) : "v"(a), "v"(b));
    return r;
}

// ---------------- fused front-end: edge hist + GRU (both layers) + X->bf16 ----------------
__global__ __launch_bounds__(256) void k_front(
    const int* __restrict__ dst, const float* __restrict__ ew, unsigned long long* dpack,
    const float* __restrict__ wi0, const float* __restrict__ wih0, const float* __restrict__ whh0,
    const float* __restrict__ bih0, const float* __restrict__ bhh0, float* __restrict__ we0,
    const float* __restrict__ wi1, const float* __restrict__ wih1, const float* __restrict__ whh1,
    const float* __restrict__ bih1, const float* __restrict__ bhh1, float* __restrict__ we1,
    const float* __restrict__ x, unsigned short* __restrict__ xb) {
    int b = blockIdx.x;
    if (b < GE_BLK) {                 // edge degree hist (packed u64 atomic)
        int e = b * 256 + threadIdx.x;
        if (e < E_EDGES) {
            unsigned pv = __float2uint_rn(ew[e] * DEG_SCALE);
            atomicAdd(&dpack[dst[e]], (1ULL << 32) | (unsigned long long)pv);
        }
    } else if (b < GE_BLK + 256) {    // GRU weight evolution
        __shared__ float xrow[C_DIM];
        int bb = b - GE_BLK;
        int layer = bb >> 7;
        int i = bb & 127, j = threadIdx.x;
        const float* w_init = layer ? wi1 : wi0;
        const float* wih = layer ? wih1 : wih0;
        const float* whh = layer ? whh1 : whh0;
        const float* bih = layer ? bih1 : bih0;
        const float* bhh = layer ? bhh1 : bhh0;
        float* w_out = layer ? we1 : we0;
        if (j < C_DIM) xrow[j] = w_init[i * C_DIM + j];
        __syncthreads();
        if (j < C_DIM) {
            float gi[3], gh[3];
#pragma unroll
            for (int g = 0; g < 3; ++g) {
                const float* wi = wih + (size_t)(g * C_DIM + j) * C_DIM;
                const float* wh = whh + (size_t)(g * C_DIM + j) * C_DIM;
                float ai = 0.f, ah = 0.f;
                for (int k = 0; k < C_DIM; ++k) { ai += xrow[k] * wi[k]; ah += xrow[k] * wh[k]; }
                gi[g] = ai + bih[g * C_DIM + j];
                gh[g] = ah + bhh[g * C_DIM + j];
            }
            float r = 1.f / (1.f + expf(-(gi[0] + gh[0])));
            float z = 1.f / (1.f + expf(-(gi[1] + gh[1])));
            float n = tanhf(gi[2] + r * gh[2]);
            w_out[i * C_DIM + j] = (1.f - z) * n + z * xrow[j];
        }
    } else {                           // X -> bf16
        int i = ((b - GE_BLK - 256) * 256 + threadIdx.x) * 8;
        f32x4 a = *(const f32x4*)(x + i);
        f32x4 bb = *(const f32x4*)(x + i + 4);
        bf16x8 o;
#pragma unroll
        for (int e = 0; e < 4; ++e) { o[e] = (short)f2bf(a[e]); o[e + 4] = (short)f2bf(bb[e]); }
        *(bf16x8*)(xb + i) = o;
    }
}

// ---------------- fused: weight prep (needs GRU) + scan1 (needs hist) ----------------
__global__ __launch_bounds__(1024) void k_ps(
    const unsigned long long* __restrict__ dpack, int* __restrict__ pos, int* __restrict__ bsum,
    const float* __restrict__ we0, const float* __restrict__ we1,
    unsigned short* __restrict__ Wc0, unsigned short* __restrict__ Wc1,
    const float* __restrict__ lw0, const float* __restrict__ lw1,
    unsigned short* __restrict__ W0p, unsigned short* __restrict__ W1p,
    const float* __restrict__ lb0, const float* __restrict__ bg0, const float* __restrict__ bb0,
    const float* __restrict__ bm0, const float* __restrict__ bv0,
    const float* __restrict__ lb1, const float* __restrict__ bg1, const float* __restrict__ bb1,
    const float* __restrict__ bm1, const float* __restrict__ bv1,
    float* __restrict__ shift0, float* __restrict__ shift1) {
    int t = threadIdx.x;
    if (blockIdx.x < 49) {   // scan1 over dpack hi32
        __shared__ int pa[1024], pb[1024];
        int x = blockIdx.x * 1024 + t;
        int v = (x < N_NODES) ? (int)(dpack[x] >> 32) : 0;
        pa[t] = v;
        __syncthreads();
        int* sp = pa; int* dp = pb;
        for (int o = 1; o < 1024; o <<= 1) {
            int u = sp[t] + ((t >= o) ? sp[t - o] : 0);
            dp[t] = u;
            __syncthreads();
            int* tmp = sp; sp = dp; dp = tmp;
        }
        if (x < N_NODES) pos[x] = sp[t];
        if (t == 1023) bsum[blockIdx.x] = sp[1023];
    } else {   // weight prep, flat id
        int pid = (blockIdx.x - 49) * 1024 + t;
        if (pid < 65536) {   // conv: [layer][kb(4)][plane][kg(4)][col(128)][e(8)]
            int idx = pid;
            int e = idx & 7, col = (idx >> 3) & 127, kg = (idx >> 10) & 3;
            int plane = (idx >> 12) & 1, kb = (idx >> 13) & 3, layer = idx >> 15;
            int k = kb * 32 + kg * 8 + e;
            const float* we = layer ? we1 : we0;
            float x = we[(size_t)k * C_DIM + col];
            unsigned short hi = f2bf(x);
            unsigned short o = plane ? f2bf(x - bf2f(hi)) : hi;
            (layer ? Wc1 : Wc0)[idx & 32767] = o;
        } else if (pid < 98304) {   // W0p hi-only: [kb][kg(4)][col(256)][e(8)]
            int idx = pid - 65536;
            int e = idx & 7, col = (idx >> 3) & 255, kg = (idx >> 11) & 3;
            int kb = idx >> 13;
            int k = kb * 32 + kg * 8 + e;
            float sc = bg0[col] * rsqrtf(bv0[col] + BN_EPS);
            W0p[idx] = f2bf(lw0[(size_t)col * C_DIM + k] * sc);
        } else if (pid < 163840) {  // W1p hi-only
            int idx = pid - 98304;
            int e = idx & 7, col = (idx >> 3) & 255, kg = (idx >> 11) & 3;
            int kb = idx >> 13;
            int k = kb * 32 + kg * 8 + e;
            float sc = bg1[col] * rsqrtf(bv1[col] + BN_EPS);
            W1p[idx] = f2bf(lw1[(size_t)col * H_DIM + k] * sc);
        } else if (pid < 164352) {  // shifts
            int j = pid - 163840;
            if (j < 256) {
                float sc = bg0[j] * rsqrtf(bv0[j] + BN_EPS);
                shift0[j] = (lb0[j] - bm0[j]) * sc + bb0[j];
            } else {
                int i = j - 256;
                float sc = bg1[i] * rsqrtf(bv1[i] + BN_EPS);
                shift1[i] = (lb1[i] - bm1[i]) * sc + bb1[i];
            }
        }
    }
}

// ---------------- scan3 with inline block-offset scan (scan2 folded in) ----------------
__global__ __launch_bounds__(1024) void k_scan3(const unsigned long long* __restrict__ dpack,
                                                int* __restrict__ pos,
                                                const int* __restrict__ bsum,
                                                int* __restrict__ off,
                                                float* __restrict__ dinv) {
    __shared__ int bo[64];
    int t = threadIdx.x;
    if (t < 64) {
        int v = (t < 49) ? bsum[t] : 0;
        int own = v;
        for (int o = 1; o < 64; o <<= 1) {
            int u = __shfl_up(v, o, 64);
            if (t >= o) v += u;
        }
        bo[t] = v - own;   // exclusive
    }
    __syncthreads();
    int x = blockIdx.x * 1024 + t;
    if (x >= N_NODES) return;
    int c = (int)(dpack[x] >> 32);
    int incl = pos[x];
    int o = bo[blockIdx.x] + incl - c;
    off[x] = o;
    pos[x] = o;
    if (x == N_NODES - 1) off[N_NODES] = o + c;
    unsigned lo = (unsigned)(dpack[x] & 0xffffffffULL);
    dinv[x] = rsqrtf(1.0f + (float)lo * (1.0f / DEG_SCALE));
}

// packed CSR entry: .x = src node, .y = float weight bits
__global__ __launch_bounds__(256) void k_fill(const int* __restrict__ src,
                                              const int* __restrict__ dst,
                                              const float* __restrict__ ew,
                                              const float* __restrict__ dinv,
                                              int* pos,
                                              int2* __restrict__ csr) {
    int e = blockIdx.x * 256 + threadIdx.x;
    if (e >= E_EDGES) return;
    int s = src[e], d = dst[e];
    int slot = atomicAdd(&pos[d], 1);
    int2 p;
    p.x = s;
    p.y = __float_as_int(dinv[s] * ew[e] * dinv[d]);
    csr[slot] = p;
}

// ---------------- CSR aggregation: 32 lanes/node, u16x4 per lane ----------------
__global__ __launch_bounds__(256) void k_agg(const unsigned short* __restrict__ xb,
                                             const float* __restrict__ dinv,
                                             const int* __restrict__ off,
                                             const int2* __restrict__ csr,
                                             float* __restrict__ agg) {
    int tid = blockIdx.x * 256 + threadIdx.x;
    int n = tid >> 5;
    int c = (tid & 31) << 2;
    float dv = dinv[n];
    float d2 = dv * dv;
    u16x4 xs = *(const u16x4*)(xb + (size_t)n * C_DIM + c);
    float4 acc;
    acc.x = d2 * bf2f(xs[0]); acc.y = d2 * bf2f(xs[1]);
    acc.z = d2 * bf2f(xs[2]); acc.w = d2 * bf2f(xs[3]);
    int i = off[n], e = off[n + 1];
    for (; i + 8 <= e; i += 8) {
        int2 q0 = csr[i], q1 = csr[i + 1], q2 = csr[i + 2], q3 = csr[i + 3];
        int2 q4 = csr[i + 4], q5 = csr[i + 5], q6 = csr[i + 6], q7 = csr[i + 7];
        u16x4 v0 = *(const u16x4*)(xb + (size_t)q0.x * C_DIM + c);
        u16x4 v1 = *(const u16x4*)(xb + (size_t)q1.x * C_DIM + c);
        u16x4 v2 = *(const u16x4*)(xb + (size_t)q2.x * C_DIM + c);
        u16x4 v3 = *(const u16x4*)(xb + (size_t)q3.x * C_DIM + c);
        u16x4 v4 = *(const u16x4*)(xb + (size_t)q4.x * C_DIM + c);
        u16x4 v5 = *(const u16x4*)(xb + (size_t)q5.x * C_DIM + c);
        u16x4 v6 = *(const u16x4*)(xb + (size_t)q6.x * C_DIM + c);
        u16x4 v7 = *(const u16x4*)(xb + (size_t)q7.x * C_DIM + c);
        float w0 = __int_as_float(q0.y), w1 = __int_as_float(q1.y);
        float w2 = __int_as_float(q2.y), w3 = __int_as_float(q3.y);
        float w4 = __int_as_float(q4.y), w5 = __int_as_float(q5.y);
        float w6 = __int_as_float(q6.y), w7 = __int_as_float(q7.y);
        acc.x += w0 * bf2f(v0[0]) + w1 * bf2f(v1[0]) + w2 * bf2f(v2[0]) + w3 * bf2f(v3[0])
               + w4 * bf2f(v4[0]) + w5 * bf2f(v5[0]) + w6 * bf2f(v6[0]) + w7 * bf2f(v7[0]);
        acc.y += w0 * bf2f(v0[1]) + w1 * bf2f(v1[1]) + w2 * bf2f(v2[1]) + w3 * bf2f(v3[1])
               + w4 * bf2f(v4[1]) + w5 * bf2f(v5[1]) + w6 * bf2f(v6[1]) + w7 * bf2f(v7[1]);
        acc.z += w0 * bf2f(v0[2]) + w1 * bf2f(v1[2]) + w2 * bf2f(v2[2]) + w3 * bf2f(v3[2])
               + w4 * bf2f(v4[2]) + w5 * bf2f(v5[2]) + w6 * bf2f(v6[2]) + w7 * bf2f(v7[2]);
        acc.w += w0 * bf2f(v0[3]) + w1 * bf2f(v1[3]) + w2 * bf2f(v2[3]) + w3 * bf2f(v3[3])
               + w4 * bf2f(v4[3]) + w5 * bf2f(v5[3]) + w6 * bf2f(v6[3]) + w7 * bf2f(v7[3]);
    }
    for (; i < e; ++i) {
        int2 pe = csr[i];
        float w = __int_as_float(pe.y);
        u16x4 v = *(const u16x4*)(xb + (size_t)pe.x * C_DIM + c);
        acc.x += w * bf2f(v[0]); acc.y += w * bf2f(v[1]);
        acc.z += w * bf2f(v[2]); acc.w += w * bf2f(v[3]);
    }
    *(float4*)(agg + (size_t)n * C_DIM + c) = acc;
}

// ---------------- conv GEMM: y = relu(agg @ W); OUT_BF: write bf16 rows ----------------
template <int OUT_BF>
__global__ __launch_bounds__(512) void k_gemm(const float* __restrict__ agg,
                                              const unsigned short* __restrict__ Wc,
                                              float* __restrict__ y,
                                              unsigned short* __restrict__ yb) {
    __shared__ __align__(16) char smem[3 * 8192];
    const int t = threadIdx.x, lane = t & 63, wave = t >> 6;
    const int qg = wave >> 1, ch = wave & 1;
    const int l16 = lane & 15, kg = lane >> 4;
    const int qrow = qg * 16 + l16;
    const int node = blockIdx.x * 64 + qrow;
    const int nodec = node < N_NODES ? node : N_NODES - 1;

    auto STG = [&](int sidx, int b) {
        const char* g = (const char*)Wc + sidx * 8192 + wave * 1024 + lane * 16;
        char* d = smem + b * 8192 + wave * 1024;
        __builtin_amdgcn_global_load_lds((const __attribute__((address_space(1))) void*)g,
                                         (__attribute__((address_space(3))) void*)d, 16, 0, 0);
    };
    STG(0, 0); STG(1, 1);

    bf16x8 bh[4], bl[4];
    const float* ar = agg + (size_t)nodec * C_DIM;
#pragma unroll
    for (int kb = 0; kb < 4; ++kb) {
        int k0 = kb * 32 + kg * 8;
        f32x4 a0 = *(const f32x4*)(ar + k0);
        f32x4 a1 = *(const f32x4*)(ar + k0 + 4);
#pragma unroll
        for (int e = 0; e < 4; ++e) {
            unsigned short h0 = f2bf(a0[e]);
            bh[kb][e] = (short)h0; bl[kb][e] = (short)f2bf(a0[e] - bf2f(h0));
            unsigned short h1 = f2bf(a1[e]);
            bh[kb][e + 4] = (short)h1; bl[kb][e + 4] = (short)f2bf(a1[e] - bf2f(h1));
        }
    }
    f32x4 acc[4];
#pragma unroll
    for (int i = 0; i < 4; ++i) acc[i] = 0.f;

#pragma unroll
    for (int s = 0; s < 8; ++s) {
        if (s < 7) { VMCNT1; } else { VMCNT0; }
        SBAR;
        if (s + 2 < 8) STG(s + 2, (s + 2) % 3);
        const unsigned short* strip = (const unsigned short*)(smem + (s % 3) * 8192);
        const int kb = s >> 1;
        __builtin_amdgcn_s_setprio(1);
#pragma unroll
        for (int jc8 = 0; jc8 < 4; ++jc8) {
            int col = (ch * 4 + jc8) * 16 + l16;
            bf16x8 a = *(const bf16x8*)&strip[kg * 1024 + col * 8];
            acc[jc8] = __builtin_amdgcn_mfma_f32_16x16x32_bf16(a, bh[kb], acc[jc8], 0, 0, 0);
            if ((s & 1) == 0)
                acc[jc8] = __builtin_amdgcn_mfma_f32_16x16x32_bf16(a, bl[kb], acc[jc8], 0, 0, 0);
        }
        __builtin_amdgcn_s_setprio(0);
    }

    if (node < N_NODES) {
#pragma unroll
        for (int jc8 = 0; jc8 < 4; ++jc8) {
            int j0 = (ch * 4 + jc8) * 16 + kg * 4;
            if (OUT_BF) {
                u16x4 v;
#pragma unroll
                for (int r = 0; r < 4; ++r) v[r] = f2bf(fmaxf(acc[jc8][r], 0.f));
                *(u16x4*)(yb + (size_t)node * C_DIM + j0) = v;
            } else {
                float4 v;
                v.x = fmaxf(acc[jc8][0], 0.f); v.y = fmaxf(acc[jc8][1], 0.f);
                v.z = fmaxf(acc[jc8][2], 0.f); v.w = fmaxf(acc[jc8][3], 0.f);
                *(float4*)(y + (size_t)node * C_DIM + j0) = v;
            }
        }
    }
}

// ---------------- fused query MLP (hi-only weights; A-dedup wave layout) ----------------
// 64 q/block, 512 thr, 8 waves = 8 col-groups of 32 (NO A-fragment duplication).
// Each wave covers all 64 queries via 4 MFMA tiles; B-frags picked per phase.
// LDS 80KB -> 2 blocks/CU: [0,48K) 3x16KB strips; [48K,80K) l1b 64x256.
__global__ __launch_bounds__(512, 4) void k_mlp(const float* __restrict__ y,
                                             const int* __restrict__ e1,
                                             const int* __restrict__ e2,
                                             const unsigned short* __restrict__ W0p,
                                             const unsigned short* __restrict__ W1p,
                                             const float* __restrict__ shift0,
                                             const float* __restrict__ shift1,
                                             const float* __restrict__ w2,
                                             const float* __restrict__ b2,
                                             float* __restrict__ out) {
    __shared__ __align__(16) char smem[81920];
    unsigned short* l1b = (unsigned short*)(smem + 49152);   // 64 x 256 shorts
    float* red = (float*)smem;                               // 4KB, epilogue only

    const int t = threadIdx.x;
    const int lane = t & 63;
    const int cg = t >> 6;               // 0..7 col-group (32 cols)
    const int l16 = lane & 15, kg = lane >> 4;
    const int qb = blockIdx.x * 64;

    auto STG = [&](const unsigned short* W, int sidx, int b) {
        const char* g = (const char*)W + ((size_t)sidx << 14) + cg * 2048 + lane * 16;
        char* d = smem + b * 16384 + cg * 2048;
        __builtin_amdgcn_global_load_lds((const __attribute__((address_space(1))) void*)g,
                                         (__attribute__((address_space(3))) void*)d, 16, 0, 0);
        __builtin_amdgcn_global_load_lds((const __attribute__((address_space(1))) void*)(g + 1024),
                                         (__attribute__((address_space(3))) void*)(d + 1024), 16, 0, 0);
    };

    STG(W0p, 0, 0); STG(W0p, 1, 1);   // overlap with phase 0

    // ---- phase 0: cooperative h staging (each query row gathered ONCE/block) ----
    {
        int k2 = lane * 2;
        int G = lane >> 2;            // k-granule 0..15
        int off = k2 & 7;
#pragma unroll
        for (int qi = 0; qi < 8; ++qi) {
            int qrow = cg * 8 + qi;
            int q = qb + qrow; if (q >= Q_PAIRS) q = Q_PAIRS - 1;
            const float* ya = y + (size_t)e1[q] * C_DIM;
            const float* yb = y + (size_t)e2[q] * C_DIM;
            float2 a = *(const float2*)(ya + k2);
            float2 b = *(const float2*)(yb + k2);
            int idx = qrow * 256 + ((G ^ (qrow & 7)) << 3) + off;
            *(unsigned*)&l1b[idx] = cvtpk(a.x * b.x, a.y * b.y);
        }
    }
    __syncthreads();   // h visible

    f32x4 acc[4][2];   // [q-tile][col-sub]
#pragma unroll
    for (int qq = 0; qq < 4; ++qq)
#pragma unroll
        for (int jc = 0; jc < 2; ++jc) acc[qq][jc] = 0.f;

    // ---- layer 1: 4 strips (hi only), per-phase B pickup, dedup'd A ----
#pragma unroll
    for (int s = 0; s < 4; ++s) {
        if (s < 3) { VMCNT2; } else { VMCNT0; }
        SBAR;
        if (s + 2 < 4) STG(W0p, s + 2, (s + 2) % 3);
        bf16x8 bh[4];
#pragma unroll
        for (int qq = 0; qq < 4; ++qq) {
            int qrow = qq * 16 + l16;
            int gidx = qrow * 256 + (((s * 4 + kg) ^ (qrow & 7)) * 8);
            bh[qq] = *(const bf16x8*)&l1b[gidx];
        }
        const unsigned short* strip = (const unsigned short*)(smem + (s % 3) * 16384);
        __builtin_amdgcn_s_setprio(1);
#pragma unroll
        for (int jc = 0; jc < 2; ++jc) {
            int col = cg * 32 + jc * 16 + l16;
            bf16x8 a = *(const bf16x8*)&strip[kg * 2048 + col * 8];
#pragma unroll
            for (int qq = 0; qq < 4; ++qq)
                acc[qq][jc] = __builtin_amdgcn_mfma_f32_16x16x32_bf16(a, bh[qq], acc[qq][jc], 0, 0, 0);
        }
        __builtin_amdgcn_s_setprio(0);
    }
    __syncthreads();   // last-phase h pickups done before epilogue overwrites l1b

    // ---- epilogue 1: BN-shift + relu -> l1b (bf16 hi only, cvt_pk pairs) ----
#pragma unroll
    for (int qq = 0; qq < 4; ++qq) {
        int qrow = qq * 16 + l16;
#pragma unroll
        for (int jc = 0; jc < 2; ++jc) {
            int jg = cg * 2 + jc;
            int j0 = jg * 16 + kg * 4;
            f32x4 sh = *(const f32x4*)(shift0 + j0);
            float v0 = fmaxf(acc[qq][jc][0] + sh[0], 0.f);
            float v1 = fmaxf(acc[qq][jc][1] + sh[1], 0.f);
            float v2 = fmaxf(acc[qq][jc][2] + sh[2], 0.f);
            float v3 = fmaxf(acc[qq][jc][3] + sh[3], 0.f);
            int G = jg * 2 + (kg >> 1);
            int idx = qrow * 256 + ((G ^ (qrow & 7)) * 8) + (kg & 1) * 4;
            uint2 pk; pk.x = cvtpk(v0, v1); pk.y = cvtpk(v2, v3);
            *(uint2*)&l1b[idx] = pk;
        }
    }
    __syncthreads();   // h1 visible; all layer-1 strip reads complete

    // ---- layer 2: 8 strips (hi only), per-phase B pickup, dedup'd A ----
    f32x4 acc2[4][2];
#pragma unroll
    for (int qq = 0; qq < 4; ++qq)
#pragma unroll
        for (int jc = 0; jc < 2; ++jc) acc2[qq][jc] = 0.f;
    STG(W1p, 0, 0); STG(W1p, 1, 1);
#pragma unroll
    for (int s = 0; s < 8; ++s) {
        if (s < 7) { VMCNT2; } else { VMCNT0; }
        SBAR;
        if (s + 2 < 8) STG(W1p, s + 2, (s + 2) % 3);
        bf16x8 bh2[4];
#pragma unroll
        for (int qq = 0; qq < 4; ++qq) {
            int qrow = qq * 16 + l16;
            int gidx = qrow * 256 + (((s * 4 + kg) ^ (qrow & 7)) * 8);
            bh2[qq] = *(const bf16x8*)&l1b[gidx];
        }
        const unsigned short* strip = (const unsigned short*)(smem + (s % 3) * 16384);
        __builtin_amdgcn_s_setprio(1);
#pragma unroll
        for (int jc = 0; jc < 2; ++jc) {
            int col = cg * 32 + jc * 16 + l16;
            bf16x8 a = *(const bf16x8*)&strip[kg * 2048 + col * 8];
#pragma unroll
            for (int qq = 0; qq < 4; ++qq)
                acc2[qq][jc] = __builtin_amdgcn_mfma_f32_16x16x32_bf16(a, bh2[qq], acc2[qq][jc], 0, 0, 0);
        }
        __builtin_amdgcn_s_setprio(0);
    }

    // ---- layer 3: BN-shift + relu + 256->2 partials ----
    float p[4][2] = {};
#pragma unroll
    for (int qq = 0; qq < 4; ++qq)
#pragma unroll
        for (int jc = 0; jc < 2; ++jc) {
            int j0 = (cg * 2 + jc) * 16 + kg * 4;
            f32x4 sh = *(const f32x4*)(shift1 + j0);
            f32x4 wa = *(const f32x4*)(w2 + j0);
            f32x4 wb = *(const f32x4*)(w2 + H_DIM + j0);
#pragma unroll
            for (int r = 0; r < 4; ++r) {
                float v = fmaxf(acc2[qq][jc][r] + sh[r], 0.f);
                p[qq][0] += v * wa[r];
                p[qq][1] += v * wb[r];
            }
        }
#pragma unroll
    for (int qq = 0; qq < 4; ++qq) {
        p[qq][0] += __shfl_xor(p[qq][0], 16, 64); p[qq][0] += __shfl_xor(p[qq][0], 32, 64);
        p[qq][1] += __shfl_xor(p[qq][1], 16, 64); p[qq][1] += __shfl_xor(p[qq][1], 32, 64);
    }
    __syncthreads();   // all strip reads done; strip region reusable as red
    if (kg == 0) {
#pragma unroll
        for (int qq = 0; qq < 4; ++qq) {
            int base = (qq * 16 + l16) * 2;
            red[(base + 0) * 8 + cg] = p[qq][0];
            red[(base + 1) * 8 + cg] = p[qq][1];
        }
    }
    __syncthreads();
    if (t < 64) {
        int q = qb + t;
        if (q < Q_PAIRS) {
            float l0 = b2[0], l1v = b2[1];
#pragma unroll
            for (int g = 0; g < 8; ++g) {
                l0 += red[(t * 2 + 0) * 8 + g];
                l1v += red[(t * 2 + 1) * 8 + g];
            }
            float mx = fmaxf(l0, l1v);
            float lse = mx + logf(expf(l0 - mx) + expf(l1v - mx));
            float2 o; o.x = l0 - lse; o.y = l1v - lse;
            *(float2*)(out + (size_t)q * N_CLS) = o;
        }
    }
}

// ---------------- launch ----------------
extern "C" void kernel_launch(void* const* d_in, const int* in_sizes, int n_in,
                              void* d_out, int out_size, void* d_ws, size_t ws_size,
                              hipStream_t stream) {
    const float* X  = (const float*)d_in[0];
    const int*   ei = (const int*)d_in[1];
    const float* ew = (const float*)d_in[2];
    const int*   e1 = (const int*)d_in[3];
    const int*   e2 = (const int*)d_in[4];
    const float* w_init[2] = {(const float*)d_in[5],  (const float*)d_in[10]};
    const float* w_ih[2]   = {(const float*)d_in[6],  (const float*)d_in[11]};
    const float* w_hh[2]   = {(const float*)d_in[7],  (const float*)d_in[12]};
    const float* b_ih[2]   = {(const float*)d_in[8],  (const float*)d_in[13]};
    const float* b_hh[2]   = {(const float*)d_in[9],  (const float*)d_in[14]};
    const float* lw0 = (const float*)d_in[15]; const float* lb0 = (const float*)d_in[16];
    const float* lw1 = (const float*)d_in[17]; const float* lb1 = (const float*)d_in[18];
    const float* lw2 = (const float*)d_in[19]; const float* lb2 = (const float*)d_in[20];
    const float* bg0 = (const float*)d_in[21]; const float* bb0 = (const float*)d_in[22];
    const float* bm0 = (const float*)d_in[23]; const float* bv0 = (const float*)d_in[24];
    const float* bg1 = (const float*)d_in[25]; const float* bb1 = (const float*)d_in[26];
    const float* bm1 = (const float*)d_in[27]; const float* bv1 = (const float*)d_in[28];
    const int* src = ei;
    const int* dst = ei + E_EDGES;

    char* ws = (char*)d_ws;
    size_t o = 0;
    auto alloc = [&](size_t bytes) { char* p = ws + o; o += (bytes + 63) & ~(size_t)63; return p; };
    float* bufA   = (float*)alloc((size_t)N_NODES * C_DIM * 4);   // agg (f32)
    float* bufB   = (float*)alloc((size_t)N_NODES * C_DIM * 4);   // y2 (f32)
    unsigned short* xbf = (unsigned short*)alloc((size_t)N_NODES * C_DIM * 2);  // X bf16
    unsigned short* ybf = (unsigned short*)alloc((size_t)N_NODES * C_DIM * 2);  // y1 bf16
    unsigned long long* dpack = (unsigned long long*)alloc((size_t)N_NODES * 8);
    float* dinv   = (float*)alloc(N_NODES * 4);
    float* we0    = (float*)alloc(C_DIM * C_DIM * 4);
    float* we1    = (float*)alloc(C_DIM * C_DIM * 4);
    float* shift0 = (float*)alloc(H_DIM * 4);
    float* shift1 = (float*)alloc(H_DIM * 4);
    int*   pos    = (int*)alloc(N_NODES * 4);
    int*   off    = (int*)alloc((N_NODES + 1) * 4);
    int*   bsum   = (int*)alloc(64 * 4);
    int2*  csr    = (int2*)alloc((size_t)E_EDGES * 8);
    unsigned short* W0p = (unsigned short*)alloc(32768 * 2);    // 64KB  (hi only)
    unsigned short* W1p = (unsigned short*)alloc(65536 * 2);    // 128KB (hi only)
    unsigned short* Wc0 = (unsigned short*)alloc(32768 * 2);    // 64KB
    unsigned short* Wc1 = (unsigned short*)alloc(32768 * 2);    // 64KB
    if (o > ws_size) return;

    dim3 b256(256);

    // front-end: memset + (hist || GRU || xbf), then (prep || scan1)
    hipMemsetAsync(dpack, 0, (size_t)N_NODES * 8, stream);
    k_front<<<GE_BLK + 256 + 3125, b256, 0, stream>>>(dst, ew, dpack,
        w_init[0], w_ih[0], w_hh[0], b_ih[0], b_hh[0], we0,
        w_init[1], w_ih[1], w_hh[1], b_ih[1], b_hh[1], we1, X, xbf);
    k_ps<<<49 + 161, dim3(1024), 0, stream>>>(dpack, pos, bsum,
        we0, we1, Wc0, Wc1, lw0, lw1, W0p, W1p,
        lb0, bg0, bb0, bm0, bv0, lb1, bg1, bb1, bm1, bv1, shift0, shift1);
    k_scan3<<<49, dim3(1024), 0, stream>>>(dpack, pos, bsum, off, dinv);
    k_fill<<<GE_BLK, b256, 0, stream>>>(src, dst, ew, dinv, pos, csr);

    const int ga = (N_NODES * 32) / 256;          // 6250
    const int gg = (N_NODES + 63) / 64;           // 782
    // layer 0: aggregate (bf16 in) -> GEMM (bf16 out)
    k_agg<<<ga, b256, 0, stream>>>(xbf, dinv, off, csr, bufA);
    k_gemm<1><<<gg, dim3(512), 0, stream>>>(bufA, Wc0, bufB, ybf);
    // layer 1: aggregate (bf16 in) -> GEMM (f32 out for MLP)
    k_agg<<<ga, b256, 0, stream>>>(ybf, dinv, off, csr, bufA);
    k_gemm<0><<<gg, dim3(512), 0, stream>>>(bufA, Wc1, bufB, ybf);
    // fused MFMA MLP (A-dedup wave layout)
    k_mlp<<<(Q_PAIRS + 63) / 64, dim3(512), 0, stream>>>(bufB, e1, e2, W0p, W1p,
                                                         shift0, shift1, lw2, lb2, (float*)d_out);
}

// Round 15
// 494.669 us; speedup vs baseline: 1.0062x; 1.0062x over previous
//
#include <hip/hip_runtime.h>
#include <math.h>

#define N_NODES 50000
#define C_DIM   128
#define E_EDGES 1600000
#define Q_PAIRS 500000
#define H_DIM   256
#define N_CLS   2
#define BN_EPS  1e-5f

#define GE_BLK  6250   // (E_EDGES+255)/256

typedef __attribute__((ext_vector_type(8))) short bf16x8;
typedef __attribute__((ext_vector_type(4))) short s16x4;
typedef __attribute__((ext_vector_type(4))) unsigned short u16x4;
typedef __attribute__((ext_vector_type(4))) float f32x4;

#define VMCNT0 asm volatile("s_waitcnt vmcnt(0)" ::: "memory")
#define VMCNT1 asm volatile("s_waitcnt vmcnt(1)" ::: "memory")
#define VMCNT2 asm volatile("s_waitcnt vmcnt(2)" ::: "memory")
#define SBAR do { __builtin_amdgcn_s_barrier(); \
                  __builtin_amdgcn_sched_barrier(0); } while (0)

#define DEG_SCALE 2097152.0f   // 2^21 fixed point for packed degree

__device__ __forceinline__ unsigned short f2bf(float x) {   // RNE f32->bf16 bits
    unsigned u = __float_as_uint(x);
    u += 0x7fffu + ((u >> 16) & 1u);
    return (unsigned short)(u >> 16);
}
__device__ __forceinline__ float bf2f(unsigned short h) {
    return __uint_as_float(((unsigned)h) << 16);
}
// packed 2x bf16 (lo=a, hi=b) via HW converter
__device__ __forceinline__ unsigned cvtpk(float a, float b) {
    unsigned r;
    asm("v_cvt_pk_bf16_f32 %0, %1, %2" : "=v"(r) : "v"(a), "v"(b));
    return r;
}

// ---------------- fused front-end: edge hist + GRU (both layers) + X->bf16 ----------------
__global__ __launch_bounds__(256) void k_front(
    const int* __restrict__ dst, const float* __restrict__ ew, unsigned long long* dpack,
    const float* __restrict__ wi0, const float* __restrict__ wih0, const float* __restrict__ whh0,
    const float* __restrict__ bih0, const float* __restrict__ bhh0, float* __restrict__ we0,
    const float* __restrict__ wi1, const float* __restrict__ wih1, const float* __restrict__ whh1,
    const float* __restrict__ bih1, const float* __restrict__ bhh1, float* __restrict__ we1,
    const float* __restrict__ x, unsigned short* __restrict__ xb) {
    int b = blockIdx.x;
    if (b < GE_BLK) {                 // edge degree hist (packed u64 atomic)
        int e = b * 256 + threadIdx.x;
        if (e < E_EDGES) {
            unsigned pv = __float2uint_rn(ew[e] * DEG_SCALE);
            atomicAdd(&dpack[dst[e]], (1ULL << 32) | (unsigned long long)pv);
        }
    } else if (b < GE_BLK + 256) {    // GRU weight evolution
        __shared__ float xrow[C_DIM];
        int bb = b - GE_BLK;
        int layer = bb >> 7;
        int i = bb & 127, j = threadIdx.x;
        const float* w_init = layer ? wi1 : wi0;
        const float* wih = layer ? wih1 : wih0;
        const float* whh = layer ? whh1 : whh0;
        const float* bih = layer ? bih1 : bih0;
        const float* bhh = layer ? bhh1 : bhh0;
        float* w_out = layer ? we1 : we0;
        if (j < C_DIM) xrow[j] = w_init[i * C_DIM + j];
        __syncthreads();
        if (j < C_DIM) {
            float gi[3], gh[3];
#pragma unroll
            for (int g = 0; g < 3; ++g) {
                const float* wi = wih + (size_t)(g * C_DIM + j) * C_DIM;
                const float* wh = whh + (size_t)(g * C_DIM + j) * C_DIM;
                float ai = 0.f, ah = 0.f;
                for (int k = 0; k < C_DIM; ++k) { ai += xrow[k] * wi[k]; ah += xrow[k] * wh[k]; }
                gi[g] = ai + bih[g * C_DIM + j];
                gh[g] = ah + bhh[g * C_DIM + j];
            }
            float r = 1.f / (1.f + expf(-(gi[0] + gh[0])));
            float z = 1.f / (1.f + expf(-(gi[1] + gh[1])));
            float n = tanhf(gi[2] + r * gh[2]);
            w_out[i * C_DIM + j] = (1.f - z) * n + z * xrow[j];
        }
    } else {                           // X -> bf16
        int i = ((b - GE_BLK - 256) * 256 + threadIdx.x) * 8;
        f32x4 a = *(const f32x4*)(x + i);
        f32x4 bb = *(const f32x4*)(x + i + 4);
        bf16x8 o;
#pragma unroll
        for (int e = 0; e < 4; ++e) { o[e] = (short)f2bf(a[e]); o[e + 4] = (short)f2bf(bb[e]); }
        *(bf16x8*)(xb + i) = o;
    }
}

// ---------------- fused: weight prep (needs GRU) + scan1 (needs hist) ----------------
__global__ __launch_bounds__(1024) void k_ps(
    const unsigned long long* __restrict__ dpack, int* __restrict__ pos, int* __restrict__ bsum,
    const float* __restrict__ we0, const float* __restrict__ we1,
    unsigned short* __restrict__ Wc0, unsigned short* __restrict__ Wc1,
    const float* __restrict__ lw0, const float* __restrict__ lw1,
    unsigned short* __restrict__ W0p, unsigned short* __restrict__ W1p,
    const float* __restrict__ lb0, const float* __restrict__ bg0, const float* __restrict__ bb0,
    const float* __restrict__ bm0, const float* __restrict__ bv0,
    const float* __restrict__ lb1, const float* __restrict__ bg1, const float* __restrict__ bb1,
    const float* __restrict__ bm1, const float* __restrict__ bv1,
    float* __restrict__ shift0, float* __restrict__ shift1) {
    int t = threadIdx.x;
    if (blockIdx.x < 49) {   // scan1 over dpack hi32
        __shared__ int pa[1024], pb[1024];
        int x = blockIdx.x * 1024 + t;
        int v = (x < N_NODES) ? (int)(dpack[x] >> 32) : 0;
        pa[t] = v;
        __syncthreads();
        int* sp = pa; int* dp = pb;
        for (int o = 1; o < 1024; o <<= 1) {
            int u = sp[t] + ((t >= o) ? sp[t - o] : 0);
            dp[t] = u;
            __syncthreads();
            int* tmp = sp; sp = dp; dp = tmp;
        }
        if (x < N_NODES) pos[x] = sp[t];
        if (t == 1023) bsum[blockIdx.x] = sp[1023];
    } else {   // weight prep, flat id
        int pid = (blockIdx.x - 49) * 1024 + t;
        if (pid < 65536) {   // conv: [layer][kb(4)][plane][kg(4)][col(128)][e(8)]
            int idx = pid;
            int e = idx & 7, col = (idx >> 3) & 127, kg = (idx >> 10) & 3;
            int plane = (idx >> 12) & 1, kb = (idx >> 13) & 3, layer = idx >> 15;
            int k = kb * 32 + kg * 8 + e;
            const float* we = layer ? we1 : we0;
            float x = we[(size_t)k * C_DIM + col];
            unsigned short hi = f2bf(x);
            unsigned short o = plane ? f2bf(x - bf2f(hi)) : hi;
            (layer ? Wc1 : Wc0)[idx & 32767] = o;
        } else if (pid < 98304) {   // W0p hi-only: [kb][kg(4)][col(256)][e(8)]
            int idx = pid - 65536;
            int e = idx & 7, col = (idx >> 3) & 255, kg = (idx >> 11) & 3;
            int kb = idx >> 13;
            int k = kb * 32 + kg * 8 + e;
            float sc = bg0[col] * rsqrtf(bv0[col] + BN_EPS);
            W0p[idx] = f2bf(lw0[(size_t)col * C_DIM + k] * sc);
        } else if (pid < 163840) {  // W1p hi-only
            int idx = pid - 98304;
            int e = idx & 7, col = (idx >> 3) & 255, kg = (idx >> 11) & 3;
            int kb = idx >> 13;
            int k = kb * 32 + kg * 8 + e;
            float sc = bg1[col] * rsqrtf(bv1[col] + BN_EPS);
            W1p[idx] = f2bf(lw1[(size_t)col * H_DIM + k] * sc);
        } else if (pid < 164352) {  // shifts
            int j = pid - 163840;
            if (j < 256) {
                float sc = bg0[j] * rsqrtf(bv0[j] + BN_EPS);
                shift0[j] = (lb0[j] - bm0[j]) * sc + bb0[j];
            } else {
                int i = j - 256;
                float sc = bg1[i] * rsqrtf(bv1[i] + BN_EPS);
                shift1[i] = (lb1[i] - bm1[i]) * sc + bb1[i];
            }
        }
    }
}

// ---------------- scan3 with inline block-offset scan ----------------
__global__ __launch_bounds__(1024) void k_scan3(const unsigned long long* __restrict__ dpack,
                                                int* __restrict__ pos,
                                                const int* __restrict__ bsum,
                                                int* __restrict__ off,
                                                float* __restrict__ dinv) {
    __shared__ int bo[64];
    int t = threadIdx.x;
    if (t < 64) {
        int v = (t < 49) ? bsum[t] : 0;
        int own = v;
        for (int o = 1; o < 64; o <<= 1) {
            int u = __shfl_up(v, o, 64);
            if (t >= o) v += u;
        }
        bo[t] = v - own;   // exclusive
    }
    __syncthreads();
    int x = blockIdx.x * 1024 + t;
    if (x >= N_NODES) return;
    int c = (int)(dpack[x] >> 32);
    int incl = pos[x];
    int o = bo[blockIdx.x] + incl - c;
    off[x] = o;
    pos[x] = o;
    if (x == N_NODES - 1) off[N_NODES] = o + c;
    unsigned lo = (unsigned)(dpack[x] & 0xffffffffULL);
    dinv[x] = rsqrtf(1.0f + (float)lo * (1.0f / DEG_SCALE));
}

// packed CSR entry: .x = src node, .y = float weight bits
__global__ __launch_bounds__(256) void k_fill(const int* __restrict__ src,
                                              const int* __restrict__ dst,
                                              const float* __restrict__ ew,
                                              const float* __restrict__ dinv,
                                              int* pos,
                                              int2* __restrict__ csr) {
    int e = blockIdx.x * 256 + threadIdx.x;
    if (e >= E_EDGES) return;
    int s = src[e], d = dst[e];
    int slot = atomicAdd(&pos[d], 1);
    int2 p;
    p.x = s;
    p.y = __float_as_int(dinv[s] * ew[e] * dinv[d]);
    csr[slot] = p;
}

// ---------------- CSR aggregation: 32 lanes/node, u16x4 per lane ----------------
__global__ __launch_bounds__(256) void k_agg(const unsigned short* __restrict__ xb,
                                             const float* __restrict__ dinv,
                                             const int* __restrict__ off,
                                             const int2* __restrict__ csr,
                                             float* __restrict__ agg) {
    int tid = blockIdx.x * 256 + threadIdx.x;
    int n = tid >> 5;
    int c = (tid & 31) << 2;
    float dv = dinv[n];
    float d2 = dv * dv;
    u16x4 xs = *(const u16x4*)(xb + (size_t)n * C_DIM + c);
    float4 acc;
    acc.x = d2 * bf2f(xs[0]); acc.y = d2 * bf2f(xs[1]);
    acc.z = d2 * bf2f(xs[2]); acc.w = d2 * bf2f(xs[3]);
    int i = off[n], e = off[n + 1];
    for (; i + 8 <= e; i += 8) {
        int2 q0 = csr[i], q1 = csr[i + 1], q2 = csr[i + 2], q3 = csr[i + 3];
        int2 q4 = csr[i + 4], q5 = csr[i + 5], q6 = csr[i + 6], q7 = csr[i + 7];
        u16x4 v0 = *(const u16x4*)(xb + (size_t)q0.x * C_DIM + c);
        u16x4 v1 = *(const u16x4*)(xb + (size_t)q1.x * C_DIM + c);
        u16x4 v2 = *(const u16x4*)(xb + (size_t)q2.x * C_DIM + c);
        u16x4 v3 = *(const u16x4*)(xb + (size_t)q3.x * C_DIM + c);
        u16x4 v4 = *(const u16x4*)(xb + (size_t)q4.x * C_DIM + c);
        u16x4 v5 = *(const u16x4*)(xb + (size_t)q5.x * C_DIM + c);
        u16x4 v6 = *(const u16x4*)(xb + (size_t)q6.x * C_DIM + c);
        u16x4 v7 = *(const u16x4*)(xb + (size_t)q7.x * C_DIM + c);
        float w0 = __int_as_float(q0.y), w1 = __int_as_float(q1.y);
        float w2 = __int_as_float(q2.y), w3 = __int_as_float(q3.y);
        float w4 = __int_as_float(q4.y), w5 = __int_as_float(q5.y);
        float w6 = __int_as_float(q6.y), w7 = __int_as_float(q7.y);
        acc.x += w0 * bf2f(v0[0]) + w1 * bf2f(v1[0]) + w2 * bf2f(v2[0]) + w3 * bf2f(v3[0])
               + w4 * bf2f(v4[0]) + w5 * bf2f(v5[0]) + w6 * bf2f(v6[0]) + w7 * bf2f(v7[0]);
        acc.y += w0 * bf2f(v0[1]) + w1 * bf2f(v1[1]) + w2 * bf2f(v2[1]) + w3 * bf2f(v3[1])
               + w4 * bf2f(v4[1]) + w5 * bf2f(v5[1]) + w6 * bf2f(v6[1]) + w7 * bf2f(v7[1]);
        acc.z += w0 * bf2f(v0[2]) + w1 * bf2f(v1[2]) + w2 * bf2f(v2[2]) + w3 * bf2f(v3[2])
               + w4 * bf2f(v4[2]) + w5 * bf2f(v5[2]) + w6 * bf2f(v6[2]) + w7 * bf2f(v7[2]);
        acc.w += w0 * bf2f(v0[3]) + w1 * bf2f(v1[3]) + w2 * bf2f(v2[3]) + w3 * bf2f(v3[3])
               + w4 * bf2f(v4[3]) + w5 * bf2f(v5[3]) + w6 * bf2f(v6[3]) + w7 * bf2f(v7[3]);
    }
    for (; i < e; ++i) {
        int2 pe = csr[i];
        float w = __int_as_float(pe.y);
        u16x4 v = *(const u16x4*)(xb + (size_t)pe.x * C_DIM + c);
        acc.x += w * bf2f(v[0]); acc.y += w * bf2f(v[1]);
        acc.z += w * bf2f(v[2]); acc.w += w * bf2f(v[3]);
    }
    *(float4*)(agg + (size_t)n * C_DIM + c) = acc;
}

// ---------------- conv GEMM: yb = bf16(relu(agg @ W)) ----------------
__global__ __launch_bounds__(512) void k_gemm(const float* __restrict__ agg,
                                              const unsigned short* __restrict__ Wc,
                                              unsigned short* __restrict__ yb) {
    __shared__ __align__(16) char smem[3 * 8192];
    const int t = threadIdx.x, lane = t & 63, wave = t >> 6;
    const int qg = wave >> 1, ch = wave & 1;
    const int l16 = lane & 15, kg = lane >> 4;
    const int qrow = qg * 16 + l16;
    const int node = blockIdx.x * 64 + qrow;
    const int nodec = node < N_NODES ? node : N_NODES - 1;

    auto STG = [&](int sidx, int b) {
        const char* g = (const char*)Wc + sidx * 8192 + wave * 1024 + lane * 16;
        char* d = smem + b * 8192 + wave * 1024;
        __builtin_amdgcn_global_load_lds((const __attribute__((address_space(1))) void*)g,
                                         (__attribute__((address_space(3))) void*)d, 16, 0, 0);
    };
    STG(0, 0); STG(1, 1);

    bf16x8 bh[4], bl[4];
    const float* ar = agg + (size_t)nodec * C_DIM;
#pragma unroll
    for (int kb = 0; kb < 4; ++kb) {
        int k0 = kb * 32 + kg * 8;
        f32x4 a0 = *(const f32x4*)(ar + k0);
        f32x4 a1 = *(const f32x4*)(ar + k0 + 4);
#pragma unroll
        for (int e = 0; e < 4; ++e) {
            unsigned short h0 = f2bf(a0[e]);
            bh[kb][e] = (short)h0; bl[kb][e] = (short)f2bf(a0[e] - bf2f(h0));
            unsigned short h1 = f2bf(a1[e]);
            bh[kb][e + 4] = (short)h1; bl[kb][e + 4] = (short)f2bf(a1[e] - bf2f(h1));
        }
    }
    f32x4 acc[4];
#pragma unroll
    for (int i = 0; i < 4; ++i) acc[i] = 0.f;

#pragma unroll
    for (int s = 0; s < 8; ++s) {
        if (s < 7) { VMCNT1; } else { VMCNT0; }
        SBAR;
        if (s + 2 < 8) STG(s + 2, (s + 2) % 3);
        const unsigned short* strip = (const unsigned short*)(smem + (s % 3) * 8192);
        const int kb = s >> 1;
        __builtin_amdgcn_s_setprio(1);
#pragma unroll
        for (int jc8 = 0; jc8 < 4; ++jc8) {
            int col = (ch * 4 + jc8) * 16 + l16;
            bf16x8 a = *(const bf16x8*)&strip[kg * 1024 + col * 8];
            acc[jc8] = __builtin_amdgcn_mfma_f32_16x16x32_bf16(a, bh[kb], acc[jc8], 0, 0, 0);
            if ((s & 1) == 0)
                acc[jc8] = __builtin_amdgcn_mfma_f32_16x16x32_bf16(a, bl[kb], acc[jc8], 0, 0, 0);
        }
        __builtin_amdgcn_s_setprio(0);
    }

    if (node < N_NODES) {
#pragma unroll
        for (int jc8 = 0; jc8 < 4; ++jc8) {
            int j0 = (ch * 4 + jc8) * 16 + kg * 4;
            u16x4 v;
#pragma unroll
            for (int r = 0; r < 4; ++r) v[r] = f2bf(fmaxf(acc[jc8][r], 0.f));
            *(u16x4*)(yb + (size_t)node * C_DIM + j0) = v;
        }
    }
}

// ---------------- fused query MLP (hi-only weights; bf16 y rows; R13 wave layout) ----------------
// 64 q/block, 512 thr, 8 waves: wave = qs*4+cg, qs in {0,1}, cg in {0..3}.
// LDS 80KB -> 2 blocks/CU: [0,48K) 3x16KB strips; [48K,80K) l1b 64x256.
__global__ __launch_bounds__(512, 4) void k_mlp(const unsigned short* __restrict__ y,
                                             const int* __restrict__ e1,
                                             const int* __restrict__ e2,
                                             const unsigned short* __restrict__ W0p,
                                             const unsigned short* __restrict__ W1p,
                                             const float* __restrict__ shift0,
                                             const float* __restrict__ shift1,
                                             const float* __restrict__ w2,
                                             const float* __restrict__ b2,
                                             float* __restrict__ out) {
    __shared__ __align__(16) char smem[81920];
    unsigned short* l1b = (unsigned short*)(smem + 49152);   // 64 x 256 shorts
    float* red = (float*)smem;                               // 2KB, epilogue only

    const int t = threadIdx.x;
    const int lane = t & 63;
    const int wave = t >> 6;
    const int qs = wave >> 2, cg = wave & 3;
    const int l16 = lane & 15, kg = lane >> 4;
    const int qb = blockIdx.x * 64;

    auto STG = [&](const unsigned short* W, int sidx, int b) {
        const char* g = (const char*)W + ((size_t)sidx << 14) + wave * 2048 + lane * 16;
        char* d = smem + b * 16384 + wave * 2048;
        __builtin_amdgcn_global_load_lds((const __attribute__((address_space(1))) void*)g,
                                         (__attribute__((address_space(3))) void*)d, 16, 0, 0);
        __builtin_amdgcn_global_load_lds((const __attribute__((address_space(1))) void*)(g + 1024),
                                         (__attribute__((address_space(3))) void*)(d + 1024), 16, 0, 0);
    };

    STG(W0p, 0, 0); STG(W0p, 1, 1);   // overlap with phase 0

    // ---- phase 0: cooperative h staging from bf16 y rows ----
    {
        int k2 = lane * 2;
        int G = lane >> 2;            // k-granule 0..15
        int off = k2 & 7;
#pragma unroll
        for (int qi = 0; qi < 8; ++qi) {
            int qrow = wave * 8 + qi;
            int q = qb + qrow; if (q >= Q_PAIRS) q = Q_PAIRS - 1;
            const unsigned short* ya = y + (size_t)e1[q] * C_DIM;
            const unsigned short* yb = y + (size_t)e2[q] * C_DIM;
            unsigned av = *(const unsigned*)(ya + k2);
            unsigned bv = *(const unsigned*)(yb + k2);
            float h0 = bf2f((unsigned short)(av & 0xffff)) * bf2f((unsigned short)(bv & 0xffff));
            float h1 = bf2f((unsigned short)(av >> 16)) * bf2f((unsigned short)(bv >> 16));
            int idx = qrow * 256 + ((G ^ (qrow & 7)) << 3) + off;
            *(unsigned*)&l1b[idx] = cvtpk(h0, h1);
        }
    }
    __syncthreads();   // h visible

    // ---- pickup h fragments into regs ----
    bf16x8 bh[2][4];
#pragma unroll
    for (int qq = 0; qq < 2; ++qq) {
        int qrow = qs * 32 + qq * 16 + l16;
#pragma unroll
        for (int kb = 0; kb < 4; ++kb) {
            int gidx = qrow * 256 + (((kb * 4 + kg) ^ (qrow & 7)) * 8);
            bh[qq][kb] = *(const bf16x8*)&l1b[gidx];
        }
    }

    f32x4 acc[2][4];
#pragma unroll
    for (int qq = 0; qq < 2; ++qq)
#pragma unroll
        for (int jc = 0; jc < 4; ++jc) acc[qq][jc] = 0.f;

    // ---- layer 1: 4 strips (hi only), depth-2 pipeline ----
#pragma unroll
    for (int s = 0; s < 4; ++s) {
        if (s < 3) { VMCNT2; } else { VMCNT0; }
        SBAR;
        if (s + 2 < 4) STG(W0p, s + 2, (s + 2) % 3);
        const unsigned short* strip = (const unsigned short*)(smem + (s % 3) * 16384);
        __builtin_amdgcn_s_setprio(1);
#pragma unroll
        for (int jc = 0; jc < 4; ++jc) {
            int col = cg * 64 + jc * 16 + l16;
            bf16x8 a = *(const bf16x8*)&strip[kg * 2048 + col * 8];
            acc[0][jc] = __builtin_amdgcn_mfma_f32_16x16x32_bf16(a, bh[0][s], acc[0][jc], 0, 0, 0);
            acc[1][jc] = __builtin_amdgcn_mfma_f32_16x16x32_bf16(a, bh[1][s], acc[1][jc], 0, 0, 0);
        }
        __builtin_amdgcn_s_setprio(0);
    }

    // ---- epilogue 1: BN-shift + relu -> l1b (bf16 hi only, cvt_pk pairs) ----
#pragma unroll
    for (int qq = 0; qq < 2; ++qq) {
        int qrow = qs * 32 + qq * 16 + l16;
#pragma unroll
        for (int jc = 0; jc < 4; ++jc) {
            int jg = cg * 4 + jc;
            int j0 = jg * 16 + kg * 4;
            f32x4 sh = *(const f32x4*)(shift0 + j0);
            float v0 = fmaxf(acc[qq][jc][0] + sh[0], 0.f);
            float v1 = fmaxf(acc[qq][jc][1] + sh[1], 0.f);
            float v2 = fmaxf(acc[qq][jc][2] + sh[2], 0.f);
            float v3 = fmaxf(acc[qq][jc][3] + sh[3], 0.f);
            int G = jg * 2 + (kg >> 1);
            int idx = qrow * 256 + ((G ^ (qrow & 7)) * 8) + (kg & 1) * 4;
            uint2 pk; pk.x = cvtpk(v0, v1); pk.y = cvtpk(v2, v3);
            *(uint2*)&l1b[idx] = pk;
        }
    }
    __syncthreads();   // h1 visible; all strip reads of layer 1 complete

    // ---- layer 2: 8 strips (hi only), depth-2 pipeline; bh2 pickup each phase ----
    f32x4 acc2[2][4];
#pragma unroll
    for (int qq = 0; qq < 2; ++qq)
#pragma unroll
        for (int jc = 0; jc < 4; ++jc) acc2[qq][jc] = 0.f;
    STG(W1p, 0, 0); STG(W1p, 1, 1);
    bf16x8 bh2[2];
#pragma unroll
    for (int s = 0; s < 8; ++s) {
        if (s < 7) { VMCNT2; } else { VMCNT0; }
        SBAR;
        if (s + 2 < 8) STG(W1p, s + 2, (s + 2) % 3);
        const unsigned short* strip = (const unsigned short*)(smem + (s % 3) * 16384);
#pragma unroll
        for (int qq = 0; qq < 2; ++qq) {
            int qrow = qs * 32 + qq * 16 + l16;
            int gidx = qrow * 256 + (((s * 4 + kg) ^ (qrow & 7)) * 8);
            bh2[qq] = *(const bf16x8*)&l1b[gidx];
        }
        __builtin_amdgcn_s_setprio(1);
#pragma unroll
        for (int jc = 0; jc < 4; ++jc) {
            int col = cg * 64 + jc * 16 + l16;
            bf16x8 a = *(const bf16x8*)&strip[kg * 2048 + col * 8];
            acc2[0][jc] = __builtin_amdgcn_mfma_f32_16x16x32_bf16(a, bh2[0], acc2[0][jc], 0, 0, 0);
            acc2[1][jc] = __builtin_amdgcn_mfma_f32_16x16x32_bf16(a, bh2[1], acc2[1][jc], 0, 0, 0);
        }
        __builtin_amdgcn_s_setprio(0);
    }

    // ---- layer 3: BN-shift + relu + 256->2 partials ----
    float p[2][2] = {};
#pragma unroll
    for (int qq = 0; qq < 2; ++qq)
#pragma unroll
        for (int jc = 0; jc < 4; ++jc) {
            int j0 = (cg * 4 + jc) * 16 + kg * 4;
            f32x4 sh = *(const f32x4*)(shift1 + j0);
            f32x4 wa = *(const f32x4*)(w2 + j0);
            f32x4 wb = *(const f32x4*)(w2 + H_DIM + j0);
#pragma unroll
            for (int r = 0; r < 4; ++r) {
                float v = fmaxf(acc2[qq][jc][r] + sh[r], 0.f);
                p[qq][0] += v * wa[r];
                p[qq][1] += v * wb[r];
            }
        }
#pragma unroll
    for (int qq = 0; qq < 2; ++qq) {
        p[qq][0] += __shfl_xor(p[qq][0], 16, 64); p[qq][0] += __shfl_xor(p[qq][0], 32, 64);
        p[qq][1] += __shfl_xor(p[qq][1], 16, 64); p[qq][1] += __shfl_xor(p[qq][1], 32, 64);
    }
    __syncthreads();   // all strip reads done; strip region reusable as red
    if (kg == 0) {
#pragma unroll
        for (int qq = 0; qq < 2; ++qq) {
            int base = ((qs * 2 + qq) * 16 + l16) * 2;
            red[(base + 0) * 4 + cg] = p[qq][0];
            red[(base + 1) * 4 + cg] = p[qq][1];
        }
    }
    __syncthreads();
    if (t < 64) {
        int q = qb + t;
        if (q < Q_PAIRS) {
            int base = t * 2;
            float l0 = red[base * 4 + 0] + red[base * 4 + 1] + red[base * 4 + 2] + red[base * 4 + 3] + b2[0];
            float l1v = red[(base + 1) * 4 + 0] + red[(base + 1) * 4 + 1]
                      + red[(base + 1) * 4 + 2] + red[(base + 1) * 4 + 3] + b2[1];
            float mx = fmaxf(l0, l1v);
            float lse = mx + logf(expf(l0 - mx) + expf(l1v - mx));
            float2 o; o.x = l0 - lse; o.y = l1v - lse;
            *(float2*)(out + (size_t)q * N_CLS) = o;
        }
    }
}

// ---------------- launch ----------------
extern "C" void kernel_launch(void* const* d_in, const int* in_sizes, int n_in,
                              void* d_out, int out_size, void* d_ws, size_t ws_size,
                              hipStream_t stream) {
    const float* X  = (const float*)d_in[0];
    const int*   ei = (const int*)d_in[1];
    const float* ew = (const float*)d_in[2];
    const int*   e1 = (const int*)d_in[3];
    const int*   e2 = (const int*)d_in[4];
    const float* w_init[2] = {(const float*)d_in[5],  (const float*)d_in[10]};
    const float* w_ih[2]   = {(const float*)d_in[6],  (const float*)d_in[11]};
    const float* w_hh[2]   = {(const float*)d_in[7],  (const float*)d_in[12]};
    const float* b_ih[2]   = {(const float*)d_in[8],  (const float*)d_in[13]};
    const float* b_hh[2]   = {(const float*)d_in[9],  (const float*)d_in[14]};
    const float* lw0 = (const float*)d_in[15]; const float* lb0 = (const float*)d_in[16];
    const float* lw1 = (const float*)d_in[17]; const float* lb1 = (const float*)d_in[18];
    const float* lw2 = (const float*)d_in[19]; const float* lb2 = (const float*)d_in[20];
    const float* bg0 = (const float*)d_in[21]; const float* bb0 = (const float*)d_in[22];
    const float* bm0 = (const float*)d_in[23]; const float* bv0 = (const float*)d_in[24];
    const float* bg1 = (const float*)d_in[25]; const float* bb1 = (const float*)d_in[26];
    const float* bm1 = (const float*)d_in[27]; const float* bv1 = (const float*)d_in[28];
    const int* src = ei;
    const int* dst = ei + E_EDGES;

    char* ws = (char*)d_ws;
    size_t o = 0;
    auto alloc = [&](size_t bytes) { char* p = ws + o; o += (bytes + 63) & ~(size_t)63; return p; };
    float* bufA   = (float*)alloc((size_t)N_NODES * C_DIM * 4);   // agg (f32)
    unsigned short* xbf = (unsigned short*)alloc((size_t)N_NODES * C_DIM * 2);  // X bf16
    unsigned short* ybf = (unsigned short*)alloc((size_t)N_NODES * C_DIM * 2);  // y1/y2 bf16
    unsigned long long* dpack = (unsigned long long*)alloc((size_t)N_NODES * 8);
    float* dinv   = (float*)alloc(N_NODES * 4);
    float* we0    = (float*)alloc(C_DIM * C_DIM * 4);
    float* we1    = (float*)alloc(C_DIM * C_DIM * 4);
    float* shift0 = (float*)alloc(H_DIM * 4);
    float* shift1 = (float*)alloc(H_DIM * 4);
    int*   pos    = (int*)alloc(N_NODES * 4);
    int*   off    = (int*)alloc((N_NODES + 1) * 4);
    int*   bsum   = (int*)alloc(64 * 4);
    int2*  csr    = (int2*)alloc((size_t)E_EDGES * 8);
    unsigned short* W0p = (unsigned short*)alloc(32768 * 2);    // 64KB  (hi only)
    unsigned short* W1p = (unsigned short*)alloc(65536 * 2);    // 128KB (hi only)
    unsigned short* Wc0 = (unsigned short*)alloc(32768 * 2);    // 64KB
    unsigned short* Wc1 = (unsigned short*)alloc(32768 * 2);    // 64KB
    if (o > ws_size) return;

    dim3 b256(256);

    // front-end: memset + (hist || GRU || xbf), then (prep || scan1)
    hipMemsetAsync(dpack, 0, (size_t)N_NODES * 8, stream);
    k_front<<<GE_BLK + 256 + 3125, b256, 0, stream>>>(dst, ew, dpack,
        w_init[0], w_ih[0], w_hh[0], b_ih[0], b_hh[0], we0,
        w_init[1], w_ih[1], w_hh[1], b_ih[1], b_hh[1], we1, X, xbf);
    k_ps<<<49 + 161, dim3(1024), 0, stream>>>(dpack, pos, bsum,
        we0, we1, Wc0, Wc1, lw0, lw1, W0p, W1p,
        lb0, bg0, bb0, bm0, bv0, lb1, bg1, bb1, bm1, bv1, shift0, shift1);
    k_scan3<<<49, dim3(1024), 0, stream>>>(dpack, pos, bsum, off, dinv);
    k_fill<<<GE_BLK, b256, 0, stream>>>(src, dst, ew, dinv, pos, csr);

    const int ga = (N_NODES * 32) / 256;          // 6250
    const int gg = (N_NODES + 63) / 64;           // 782
    // layer 0: aggregate (bf16 in) -> GEMM (bf16 out)
    k_agg<<<ga, b256, 0, stream>>>(xbf, dinv, off, csr, bufA);
    k_gemm<<<gg, dim3(512), 0, stream>>>(bufA, Wc0, ybf);
    // layer 1: aggregate (bf16 in) -> GEMM (bf16 out; gemm2 never reads ybf)
    k_agg<<<ga, b256, 0, stream>>>(ybf, dinv, off, csr, bufA);
    k_gemm<<<gg, dim3(512), 0, stream>>>(bufA, Wc1, ybf);
    // fused MFMA MLP (bf16 y rows)
    k_mlp<<<(Q_PAIRS + 63) / 64, dim3(512), 0, stream>>>(ybf, e1, e2, W0p, W1p,
                                                         shift0, shift1, lw2, lb2, (float*)d_out);
}